// Round 4
// baseline (231.449 us; speedup 1.0000x reference)
//
#include <hip/hip_runtime.h>

// TemporalPSPGate: state_t = ALPHA*state_{t-1} + x_t ; out_t = x_t * sigmoid(state_t)
// x: (T,B,H,N,D) = (16,16,8,256,64) fp32.
//
// Session journal (dur = kernel + ~163us fixed harness fills):
// R1: load->use serialization, kernel 83us.
// R2: 16-deep register prefetch -> kernel ~66us.
// R3: nt loads/stores + v_rcp: NEUTRAL. Cache-churn theory dead.
// R4: 8 waves/SIMD occupancy: NEUTRAL. TLP theory dead.
// R5: WIN. 4KB contiguous per-wave runs (SUB=4): dur 230->217.6, kernel ~54.5us
//     (4.9 TB/s). Run-length/stream-count is the real mechanism.
// R6 (this): same lever, doubled. SUB=8 -> 8KB contiguous load runs + 8KB store
//   runs per slice, ~half the concurrent DRAM streams. Grid 256 blocks (1/CU,
//   4 waves/CU) -- TLP bounded-safe: in-flight = 16MB >> 6MB BW*latency.
//   Even/odd-phase macro keeps all indices static (no scratch).
//   Predicted: kernel -> 48-52us, dur -> 211-215. Neutral/regress -> roofline
//   (residual = R/W turnaround on 1:1 mixed stream).

#define T_STEPS 16
#define SPATIAL (16LL * 8LL * 256LL * 64LL)   // B*H*N*D = 2,097,152 floats per t
#define VEC4    (SPATIAL / 4)                 // 524,288 float4 slots per t
#define ALPHA_F 0.60653065971263342f          // exp(-1/2)
#define SUB     8                             // consecutive wave-chunks per thread

typedef float f32x4 __attribute__((ext_vector_type(4)));

__global__ __launch_bounds__(256) void
TemporalPSPGate_35613868819159_kernel(const f32x4* __restrict__ x,
                                      f32x4* __restrict__ out) {
    // wave w of block b owns f4 slots [wb, wb+512) per slice; lane handles
    // wb+lane+64*s for s=0..7 -> 8 back-to-back 1KB wave-loads = one 8KB
    // contiguous run per slice; stores likewise grouped into an 8KB run.
    const int tid  = threadIdx.x;
    const int wave = tid >> 6;
    const int lane = tid & 63;
    const long long wb = ((long long)blockIdx.x * 4 + wave) * (64 * SUB);
    const long long j  = wb + lane;            // base f4 slot

    f32x4 bufA[SUB], bufB[SUB], xt[SUB], st[SUB];

    #pragma unroll
    for (int s = 0; s < SUB; ++s)
        bufA[s] = __builtin_nontemporal_load(x + j + 64 * s);
    #pragma unroll
    for (int s = 0; s < SUB; ++s)
        bufB[s] = __builtin_nontemporal_load(x + VEC4 + j + 64 * s);
    #pragma unroll
    for (int s = 0; s < SUB; ++s) st[s] = (f32x4){0.f, 0.f, 0.f, 0.f};

    // One pipeline step at compile-time slice T, consuming buffer CURBUF and
    // refilling it with slice T+2 as one grouped 8KB load run before compute.
    #define STEP(T, CURBUF)                                                   \
    {                                                                         \
        _Pragma("unroll")                                                     \
        for (int s = 0; s < SUB; ++s) xt[s] = CURBUF[s];                      \
        if ((T) + 2 < T_STEPS) {                                              \
            _Pragma("unroll")                                                 \
            for (int s = 0; s < SUB; ++s)                                     \
                CURBUF[s] = __builtin_nontemporal_load(                       \
                    x + (long long)((T) + 2) * VEC4 + j + 64 * s);            \
        }                                                                     \
        _Pragma("unroll")                                                     \
        for (int s = 0; s < SUB; ++s) {                                       \
            st[s] = ALPHA_F * st[s] + xt[s];                                  \
            f32x4 o;                                                          \
            _Pragma("unroll")                                                 \
            for (int c = 0; c < 4; ++c) {                                     \
                const float e = __expf(-st[s][c]);                            \
                o[c] = xt[s][c] * __builtin_amdgcn_rcpf(1.0f + e);            \
            }                                                                 \
            out[(long long)(T) * VEC4 + j + 64 * s] = o;                      \
        }                                                                     \
    }

    #pragma unroll
    for (int tt = 0; tt < T_STEPS; tt += 2) {
        STEP(tt,     bufA);
        STEP(tt + 1, bufB);
    }
    #undef STEP
}

extern "C" void kernel_launch(void* const* d_in, const int* in_sizes, int n_in,
                              void* d_out, int out_size, void* d_ws, size_t ws_size,
                              hipStream_t stream) {
    const f32x4* x = (const f32x4*)d_in[0];
    f32x4* out = (f32x4*)d_out;

    const int block = 256;
    const int grid = (int)(VEC4 / (block * SUB));   // 256 blocks, no tail

    TemporalPSPGate_35613868819159_kernel<<<grid, block, 0, stream>>>(x, out);
}

// Round 5
// 217.118 us; speedup vs baseline: 1.0660x; 1.0660x over previous
//
#include <hip/hip_runtime.h>

// TemporalPSPGate: state_t = ALPHA*state_{t-1} + x_t ; out_t = x_t * sigmoid(state_t)
// x: (T,B,H,N,D) = (16,16,8,256,64) fp32.
//
// Session journal (dur = kernel + ~160us fixed harness fills):
// R1: load->use serialization, kernel 83us.
// R2: 16-deep register prefetch -> kernel ~66us.
// R3: nt loads/stores + v_rcp: NEUTRAL. Cache-churn theory dead.
// R4: 8 waves/SIMD occupancy: NEUTRAL (at 1KB interleave). TLP-alone theory dead.
// R5: WIN. SUB=4: per-wave 4KB contiguous runs, 512 blocks (8 waves/CU):
//     dur 217.6, kernel ~54.5us = 4.9 TB/s.
// R6: SUB=8 (8KB runs, 4 waves/CU): REGRESS, kernel ~72us. 1 wave/SIMD too few;
//     R5 is the run-length/occupancy knee.
// R7 (this): hold R5's mapping (SUB=4, 512 blocks, 8 waves/CU) but halve the
//   R/W direction-switch frequency: superstep = 2 slices. Per superstep:
//   8 grouped nt loads (slices t+2,t+3) -> compute both -> 8 grouped stores
//   (slices t,t+1). Read bursts 8KB, write bursts 8KB, occupancy unchanged.
//   Predicted: kernel -> 48-51us, dur -> 211-215. Neutral -> R5 is the mixed
//   R/W roofline (~5 TB/s vs 6.45 pure-write fill); regress -> revert to R5.

#define T_STEPS 16
#define SPATIAL (16LL * 8LL * 256LL * 64LL)   // B*H*N*D = 2,097,152 floats per t
#define VEC4    (SPATIAL / 4)                 // 524,288 float4 slots per t
#define ALPHA_F 0.60653065971263342f          // exp(-1/2)
#define SUB     4                             // consecutive wave-chunks per thread

typedef float f32x4 __attribute__((ext_vector_type(4)));

__global__ __launch_bounds__(256) void
TemporalPSPGate_35613868819159_kernel(const f32x4* __restrict__ x,
                                      f32x4* __restrict__ out) {
    // Same spatial mapping as R5: wave owns [wb, wb+256) f4 slots per slice;
    // lane handles wb+lane+64*s, s=0..3 -> 4KB contiguous run per slice.
    const int tid  = threadIdx.x;
    const int wave = tid >> 6;
    const int lane = tid & 63;
    const long long wb = ((long long)blockIdx.x * 4 + wave) * (64 * SUB);
    const long long j  = wb + lane;            // base f4 slot

    // Two 8-slot buffers, each holding a PAIR of slices (q>>2 = slice-in-pair,
    // q&3 = chunk). All indices compile-time (no scratch).
    f32x4 bufA[8], bufB[8], xt[8], st[SUB];

    #pragma unroll
    for (int q = 0; q < 8; ++q)
        bufA[q] = __builtin_nontemporal_load(
            x + (long long)(q >> 2) * VEC4 + j + 64 * (q & 3));        // slices 0,1
    #pragma unroll
    for (int q = 0; q < 8; ++q)
        bufB[q] = __builtin_nontemporal_load(
            x + (long long)(2 + (q >> 2)) * VEC4 + j + 64 * (q & 3));  // slices 2,3
    #pragma unroll
    for (int s = 0; s < SUB; ++s) st[s] = (f32x4){0.f, 0.f, 0.f, 0.f};

    // Superstep: consume BUF (slices TT,TT+1), refill with TT+4,TT+5 (8 grouped
    // loads), compute both slices, then 8 grouped stores.
    #define SSTEP(TT, BUF)                                                    \
    {                                                                         \
        _Pragma("unroll")                                                     \
        for (int q = 0; q < 8; ++q) xt[q] = BUF[q];                           \
        if ((TT) + 4 < T_STEPS) {                                             \
            _Pragma("unroll")                                                 \
            for (int q = 0; q < 8; ++q)                                       \
                BUF[q] = __builtin_nontemporal_load(                          \
                    x + (long long)((TT) + 4 + (q >> 2)) * VEC4               \
                      + j + 64 * (q & 3));                                    \
        }                                                                     \
        f32x4 o[8];                                                           \
        _Pragma("unroll")                                                     \
        for (int q = 0; q < 8; ++q) {                                         \
            const int s = q & 3;  /* q=0..3: slice TT; q=4..7: slice TT+1 */  \
            st[s] = ALPHA_F * st[s] + xt[q];                                  \
            _Pragma("unroll")                                                 \
            for (int c = 0; c < 4; ++c) {                                     \
                const float e = __expf(-st[s][c]);                            \
                o[q][c] = xt[q][c] * __builtin_amdgcn_rcpf(1.0f + e);         \
            }                                                                 \
        }                                                                     \
        _Pragma("unroll")                                                     \
        for (int q = 0; q < 8; ++q)                                           \
            out[(long long)((TT) + (q >> 2)) * VEC4 + j + 64 * (q & 3)]       \
                = o[q];                                                       \
    }

    #pragma unroll
    for (int tt = 0; tt < T_STEPS; tt += 4) {
        SSTEP(tt,     bufA);
        SSTEP(tt + 2, bufB);
    }
    #undef SSTEP
}

extern "C" void kernel_launch(void* const* d_in, const int* in_sizes, int n_in,
                              void* d_out, int out_size, void* d_ws, size_t ws_size,
                              hipStream_t stream) {
    const f32x4* x = (const f32x4*)d_in[0];
    f32x4* out = (f32x4*)d_out;

    const int block = 256;
    const int grid = (int)(VEC4 / (block * SUB));   // 512 blocks (2/CU, 8 waves/CU)

    TemporalPSPGate_35613868819159_kernel<<<grid, block, 0, stream>>>(x, out);
}